// Round 2
// baseline (1847.780 us; speedup 1.0000x reference)
//
#include <hip/hip_runtime.h>

typedef unsigned short u16;
typedef short s8v __attribute__((ext_vector_type(8)));
typedef float f4v __attribute__((ext_vector_type(4)));

__device__ __forceinline__ float bf2f(u16 s) {
  unsigned u = ((unsigned)s) << 16;
  return __builtin_bit_cast(float, u);
}
__device__ __forceinline__ u16 f2bf(float f) {
  unsigned u = __builtin_bit_cast(unsigned, f);
  unsigned r = u + 0x7fffu + ((u >> 16) & 1u);  // RNE (no NaN here)
  return (u16)(r >> 16);
}
__device__ __forceinline__ s8v load8bf(const u16* p) {
  return __builtin_bit_cast(s8v, *(const uint4*)p);
}
__device__ __forceinline__ f4v mfma16(s8v a, s8v b, f4v c) {
  return __builtin_amdgcn_mfma_f32_16x16x32_bf16(a, b, c, 0, 0, 0);
}
// 8 consecutive f32 -> bf16 hi + bf16 lo fragments (split precision)
__device__ __forceinline__ void cvt8(const float* p, s8v& hi, s8v& lo) {
  float4 x0 = ((const float4*)p)[0];
  float4 x1 = ((const float4*)p)[1];
  float v[8] = {x0.x, x0.y, x0.z, x0.w, x1.x, x1.y, x1.z, x1.w};
  union { s8v v; u16 a[8]; } H, L;
#pragma unroll
  for (int i = 0; i < 8; ++i) {
    u16 h = f2bf(v[i]);
    H.a[i] = h;
    L.a[i] = f2bf(v[i] - bf2f(h));
  }
  hi = H.v;
  lo = L.v;
}

// ---------------------------------------------------------------------------
// Prep: (a) transpose g_Whh{0,1} f32 [j][k] -> f32 [k][j];
//       (b) convert e_Whh0/e_Wih1/e_Whh1 f32 -> bf16 (row-major unchanged).
// ---------------------------------------------------------------------------
__global__ void k_prep(const float* __restrict__ W0, const float* __restrict__ W1,
                       float* __restrict__ Wt0, float* __restrict__ Wt1,
                       const float* __restrict__ E0, const float* __restrict__ E1,
                       const float* __restrict__ E2, u16* __restrict__ B0,
                       u16* __restrict__ B1, u16* __restrict__ B2) {
  int t = blockIdx.x * 256 + threadIdx.x;  // 327680 total
  if (t < 131072) {
    int layer = t >> 16;
    int idx = t & 65535;
    int k = idx >> 8, j = idx & 255;
    const float* W = layer ? W1 : W0;
    float* Wt = layer ? Wt1 : Wt0;
    Wt[k * 256 + j] = W[j * 256 + k];
  } else {
    int c = t - 131072;
    int which = c >> 16;
    int idx = c & 65535;
    const float* src = which == 0 ? E0 : (which == 1 ? E1 : E2);
    u16* dst = which == 0 ? B0 : (which == 1 ? B1 : B2);
    dst[idx] = f2bf(src[idx]);
  }
}

// ---------------------------------------------------------------------------
// xw0 = X @ g_Wih0^T + bih0 + bhh0 (split-bf16 MFMA, f32-accurate).
// X row n=(b,s): s==0 -> sentinel else input[b][s-1]. grid (128,4) x 256.
// ---------------------------------------------------------------------------
__launch_bounds__(256)
__global__ void k_xw0(const float* __restrict__ input, const float* __restrict__ sentinel,
                      const float* __restrict__ W, const float* __restrict__ b1,
                      const float* __restrict__ b2, float* __restrict__ outxw) {
  const int l = threadIdx.x & 63;
  const int wv = threadIdx.x >> 6;
  const int l15 = l & 15, q = l >> 4;
  const int row0 = blockIdx.x * 64 + wv * 16;
  const int col0 = blockIdx.y * 64;
  int row = row0 + l15;
  int s = row & 511, b = row >> 9;
  const float* aptr = (s == 0) ? sentinel : input + (((size_t)(b * 511 + s - 1)) << 9);
  f4v acc[4];
#pragma unroll
  for (int i = 0; i < 4; ++i) acc[i] = (f4v){0.f, 0.f, 0.f, 0.f};
#pragma unroll
  for (int kt = 0; kt < 16; ++kt) {
    int k0 = kt * 32 + q * 8;
    s8v ah, al;
    cvt8(aptr + k0, ah, al);
#pragma unroll
    for (int nt = 0; nt < 4; ++nt) {
      int j = col0 + nt * 16 + l15;
      s8v wh, wl;
      cvt8(W + ((size_t)j << 9) + k0, wh, wl);
      acc[nt] = mfma16(ah, wh, acc[nt]);
      acc[nt] = mfma16(al, wh, acc[nt]);
      acc[nt] = mfma16(ah, wl, acc[nt]);
    }
  }
#pragma unroll
  for (int nt = 0; nt < 4; ++nt) {
    int col = col0 + nt * 16 + l15;
    float bias = b1[col] + b2[col];
#pragma unroll
    for (int r = 0; r < 4; ++r) {
      int rr = row0 + q * 4 + r;
      outxw[((size_t)rr << 8) + col] = acc[nt][r] + bias;
    }
  }
}

// ---------------------------------------------------------------------------
// Generic split-bf16 C = act(A @ W^T + b1 (+b2)); A f32 [N][K], W f32 [J][K].
// act=0: identity; act=1: elu. Output f32 [N][J]. grid (N/64, J/64) x 256.
// ---------------------------------------------------------------------------
__launch_bounds__(256)
__global__ void k_gemm(const float* __restrict__ A, const float* __restrict__ W,
                       const float* __restrict__ b1, const float* __restrict__ b2,
                       float* __restrict__ outf, int K, int J, int act) {
  const int l = threadIdx.x & 63;
  const int wv = threadIdx.x >> 6;
  const int l15 = l & 15, q = l >> 4;
  const int row0 = blockIdx.x * 64 + wv * 16;
  const int col0 = blockIdx.y * 64;
  const float* aptr = A + (size_t)(row0 + l15) * K;
  f4v acc[4];
#pragma unroll
  for (int i = 0; i < 4; ++i) acc[i] = (f4v){0.f, 0.f, 0.f, 0.f};
  const int nkt = K >> 5;
  for (int kt = 0; kt < nkt; ++kt) {
    int k0 = kt * 32 + q * 8;
    s8v ah, al;
    cvt8(aptr + k0, ah, al);
#pragma unroll
    for (int nt = 0; nt < 4; ++nt) {
      int j = col0 + nt * 16 + l15;
      s8v wh, wl;
      cvt8(W + (size_t)j * K + k0, wh, wl);
      acc[nt] = mfma16(ah, wh, acc[nt]);
      acc[nt] = mfma16(al, wh, acc[nt]);
      acc[nt] = mfma16(ah, wl, acc[nt]);
    }
  }
#pragma unroll
  for (int nt = 0; nt < 4; ++nt) {
    int col = col0 + nt * 16 + l15;
    float bias = b1[col] + (b2 ? b2[col] : 0.f);
#pragma unroll
    for (int r = 0; r < 4; ++r) {
      int rr = row0 + q * 4 + r;
      float v = acc[nt][r] + bias;
      if (act) v = v > 0.f ? v : expm1f(v);
      outf[(size_t)rr * J + col] = v;
    }
  }
}

// ---------------------------------------------------------------------------
// Sequential RNN scan, one wg per batch row, pure f32.
// Wt: f32 [k][j]. 1024 threads: tid = p*256+j; thread holds 64 Wt values.
// outf[n*256+j] = h * mask (f32); recurrence uses unmasked h.
// ---------------------------------------------------------------------------
__launch_bounds__(1024)
__global__ void k_scan(const float* __restrict__ xw, const float* __restrict__ Wt,
                       float* __restrict__ outf, const int* __restrict__ mask) {
  __shared__ __align__(16) float hcur[256];
  __shared__ float partials[1024];
  const int tid = threadIdx.x;
  const int p = tid >> 8, j = tid & 255;
  const int b = blockIdx.x;
  float wreg[64];
#pragma unroll
  for (int i = 0; i < 64; ++i) wreg[i] = Wt[(p * 64 + i) * 256 + j];
  if (tid < 256) hcur[tid] = 0.f;
  __syncthreads();
  const float4* hc4 = (const float4*)hcur;
  for (int s = 0; s < 512; ++s) {
    float partial = 0.f;
#pragma unroll
    for (int i4 = 0; i4 < 16; ++i4) {
      float4 h4 = hc4[p * 16 + i4];
      partial = __builtin_fmaf(h4.x, wreg[i4 * 4 + 0], partial);
      partial = __builtin_fmaf(h4.y, wreg[i4 * 4 + 1], partial);
      partial = __builtin_fmaf(h4.z, wreg[i4 * 4 + 2], partial);
      partial = __builtin_fmaf(h4.w, wreg[i4 * 4 + 3], partial);
    }
    partials[tid] = partial;
    __syncthreads();
    if (tid < 256) {
      size_t n = ((size_t)b << 9) + s;
      float v = partials[j] + partials[256 + j] + partials[512 + j] + partials[768 + j] +
                xw[(n << 8) + j];
      float h = tanhf(v);
      hcur[j] = h;
      float ho = h;
      if (mask) {
        int mv = (s == 0) ? 1 : mask[b * 511 + s - 1];
        ho = h * (float)mv;
      }
      outf[(n << 8) + j] = ho;
    }
    __syncthreads();
  }
}

// ---------------------------------------------------------------------------
// Encoder: 32 steps, 32 rows/wg, 512 threads (2 mtiles x 4 n-groups of waves).
// h0/h1 bf16 in LDS; weights pre-converted bf16 streamed from L2.
// ---------------------------------------------------------------------------
__launch_bounds__(512)
__global__ void k_enc(const float* __restrict__ gs,
                      const u16* __restrict__ Whh0, const u16* __restrict__ Wih1,
                      const u16* __restrict__ Whh1, const float* __restrict__ wih0,
                      const float* __restrict__ bih0, const float* __restrict__ bhh0,
                      const float* __restrict__ bih1, const float* __restrict__ bhh1,
                      const float* __restrict__ clsW, const float* __restrict__ clsb,
                      float* __restrict__ Ab) {
  __shared__ __align__(16) u16 hA0[32 * 264];
  __shared__ __align__(16) u16 hA1[32 * 264];
  __shared__ float xe[32];
  __shared__ float b0v[256], w0v[256], b1v[256], clsv[256];
  __shared__ float clsbs;
  const int tid = threadIdx.x;
  const int n0 = blockIdx.x * 32;

  for (int c = tid; c < 8192; c += 512) {
    int row = c >> 8, col = c & 255;
    hA0[row * 264 + col] = f2bf(gs[(((size_t)(n0 + row)) << 8) + col]);
    hA1[row * 264 + col] = 0;
  }
  if (tid < 256) {
    b0v[tid] = bih0[tid] + bhh0[tid];
    w0v[tid] = wih0[tid];
    b1v[tid] = bih1[tid] + bhh1[tid];
    clsv[tid] = clsW[tid];
  }
  if (tid < 32) xe[tid] = 1.0f;
  if (tid == 0) clsbs = clsb[0];
  __syncthreads();

  const int l = tid & 63, wv = tid >> 6;
  const int l15 = l & 15, q = l >> 4;
  const int mt = wv & 1, ng = wv >> 1;
  const int arow = (mt * 16 + l15) * 264 + q * 8;

  for (int m = 0; m < 32; ++m) {
    // pass 1: acc = h0 @ Whh0^T
    f4v acc[4];
#pragma unroll
    for (int i = 0; i < 4; ++i) acc[i] = (f4v){0.f, 0.f, 0.f, 0.f};
#pragma unroll
    for (int kt = 0; kt < 8; ++kt) {
      s8v a = __builtin_bit_cast(s8v, *(const uint4*)&hA0[arow + kt * 32]);
#pragma unroll
      for (int i = 0; i < 4; ++i) {
        int jj = (ng * 4 + i) * 16 + l15;
        s8v bb = load8bf(Whh0 + ((size_t)jj << 8) + kt * 32 + q * 8);
        acc[i] = mfma16(a, bb, acc[i]);
      }
    }
    __syncthreads();
    // epilogue 1: h0 = tanh(acc + xe*w0 + b0)
#pragma unroll
    for (int i = 0; i < 4; ++i) {
      int col = (ng * 4 + i) * 16 + l15;
#pragma unroll
      for (int r = 0; r < 4; ++r) {
        int row = mt * 16 + q * 4 + r;
        float v = acc[i][r] + xe[row] * w0v[col] + b0v[col];
        hA0[row * 264 + col] = f2bf(tanhf(v));
      }
    }
    __syncthreads();
    // pass 2: acc = h0new @ Wih1^T + h1 @ Whh1^T
#pragma unroll
    for (int i = 0; i < 4; ++i) acc[i] = (f4v){0.f, 0.f, 0.f, 0.f};
#pragma unroll
    for (int kt = 0; kt < 8; ++kt) {
      s8v a = __builtin_bit_cast(s8v, *(const uint4*)&hA0[arow + kt * 32]);
#pragma unroll
      for (int i = 0; i < 4; ++i) {
        int jj = (ng * 4 + i) * 16 + l15;
        s8v bb = load8bf(Wih1 + ((size_t)jj << 8) + kt * 32 + q * 8);
        acc[i] = mfma16(a, bb, acc[i]);
      }
    }
#pragma unroll
    for (int kt = 0; kt < 8; ++kt) {
      s8v a = __builtin_bit_cast(s8v, *(const uint4*)&hA1[arow + kt * 32]);
#pragma unroll
      for (int i = 0; i < 4; ++i) {
        int jj = (ng * 4 + i) * 16 + l15;
        s8v bb = load8bf(Whh1 + ((size_t)jj << 8) + kt * 32 + q * 8);
        acc[i] = mfma16(a, bb, acc[i]);
      }
    }
    __syncthreads();
    // epilogue 2: h1 = tanh(acc + b1)
#pragma unroll
    for (int i = 0; i < 4; ++i) {
      int col = (ng * 4 + i) * 16 + l15;
#pragma unroll
      for (int r = 0; r < 4; ++r) {
        int row = mt * 16 + q * 4 + r;
        float v = acc[i][r] + b1v[col];
        hA1[row * 264 + col] = f2bf(tanhf(v));
      }
    }
    __syncthreads();
    // cls: p = sigmoid(h1 @ clsW^T + clsb); xe <- p; Ab[n*32+m] = p
    if (tid < 256) {
      int row = tid >> 3, seg = tid & 7;
      float sum = 0.f;
#pragma unroll
      for (int u = 0; u < 4; ++u) {
        int col = seg * 32 + u * 8;
#pragma unroll
        for (int e = 0; e < 8; ++e) sum += bf2f(hA1[row * 264 + col + e]) * clsv[col + e];
      }
      sum += __shfl_down(sum, 4, 8);
      sum += __shfl_down(sum, 2, 8);
      sum += __shfl_down(sum, 1, 8);
      if (seg == 0) {
        float pp = 1.f / (1.f + expf(-(sum + clsbs)));
        xe[row] = pp;
        Ab[(((size_t)(n0 + row)) << 5) + m] = pp;
      }
    }
    __syncthreads();
  }
}

// ---------------------------------------------------------------------------
// arc_logits[b][j][i] = (j>=max(0,i-32) && j<i) ? Ab[(b*512+i)*32 + j-start] : 0
// ---------------------------------------------------------------------------
__global__ void k_arc(const float* __restrict__ Ab, float* __restrict__ out2) {
  int t = blockIdx.x * 256 + threadIdx.x;  // 4194304 total
  int b = t >> 18;
  int rem = t & 262143;
  int j = rem >> 9, i = rem & 511;
  int start = i - 32;
  if (start < 0) start = 0;
  float v = 0.f;
  if (j >= start && j < i) v = Ab[((((size_t)b << 9) + i) << 5) + (j - start)];
  out2[t] = v;
}

// ---------------------------------------------------------------------------
extern "C" void kernel_launch(void* const* d_in, const int* in_sizes, int n_in,
                              void* d_out, int out_size, void* d_ws, size_t ws_size,
                              hipStream_t stream) {
  const float* input    = (const float*)d_in[0];
  const float* sentinel = (const float*)d_in[1];
  const float* g_Wih0   = (const float*)d_in[2];
  const float* g_Whh0   = (const float*)d_in[3];
  const float* g_bih0   = (const float*)d_in[4];
  const float* g_bhh0   = (const float*)d_in[5];
  const float* g_Wih1   = (const float*)d_in[6];
  const float* g_Whh1   = (const float*)d_in[7];
  const float* g_bih1   = (const float*)d_in[8];
  const float* g_bhh1   = (const float*)d_in[9];
  const float* e_Wih0   = (const float*)d_in[10];
  const float* e_Whh0   = (const float*)d_in[11];
  const float* e_bih0   = (const float*)d_in[12];
  const float* e_bhh0   = (const float*)d_in[13];
  const float* e_Wih1   = (const float*)d_in[14];
  const float* e_Whh1   = (const float*)d_in[15];
  const float* e_bih1   = (const float*)d_in[16];
  const float* e_bhh1   = (const float*)d_in[17];
  const float* cls_W    = (const float*)d_in[18];
  const float* cls_b    = (const float*)d_in[19];
  const float* head_W   = (const float*)d_in[20];
  const float* head_b   = (const float*)d_in[21];
  const float* dep_W    = (const float*)d_in[22];
  const float* dep_b    = (const float*)d_in[23];
  const int* mask       = (const int*)d_in[24];

  float* out = (float*)d_out;
  char* ws = (char*)d_ws;
  float* xw_buf = (float*)ws;                                 // 8 MB
  float* hseq   = (float*)(ws + (8u << 20));                  // 8 MB
  float* gsb    = (float*)(ws + (16u << 20));                 // 8 MB
  float* Ab     = (float*)(ws + (24u << 20));                 // 1 MB
  float* Wt0    = (float*)(ws + (25u << 20));                 // 256 KB
  float* Wt1    = (float*)(ws + (25u << 20) + (256u << 10));  // 256 KB
  u16* eb0      = (u16*)(ws + (26u << 20));                   // 128 KB
  u16* eb1      = (u16*)(ws + (26u << 20) + (128u << 10));    // 128 KB
  u16* eb2      = (u16*)(ws + (26u << 20) + (256u << 10));    // 128 KB

  k_prep<<<1280, 256, 0, stream>>>(g_Whh0, g_Whh1, Wt0, Wt1, e_Whh0, e_Wih1, e_Whh1,
                                   eb0, eb1, eb2);
  k_xw0<<<dim3(128, 4), 256, 0, stream>>>(input, sentinel, g_Wih0, g_bih0, g_bhh0, xw_buf);
  k_scan<<<16, 1024, 0, stream>>>(xw_buf, Wt0, hseq, nullptr);
  k_gemm<<<dim3(128, 4), 256, 0, stream>>>(hseq, g_Wih1, g_bih1, g_bhh1, xw_buf, 256, 256, 0);
  k_scan<<<16, 1024, 0, stream>>>(xw_buf, Wt1, gsb, mask);
  k_gemm<<<dim3(128, 2), 256, 0, stream>>>(gsb, head_W, head_b, nullptr, out, 256, 128, 1);
  k_gemm<<<dim3(128, 2), 256, 0, stream>>>(gsb, dep_W, dep_b, nullptr, out + 1048576,
                                           256, 128, 1);
  k_enc<<<256, 512, 0, stream>>>(gsb, eb0, eb1, eb2, e_Wih0, e_bih0, e_bhh0,
                                 e_bih1, e_bhh1, cls_W, cls_b, Ab);
  k_arc<<<16384, 256, 0, stream>>>(Ab, out + 2097152);
}